// Round 11
// baseline (284.969 us; speedup 1.0000x reference)
//
#include <hip/hip_runtime.h>
#include <stdint.h>

#define BATCH 524288
#define OBSD  64

typedef short v8s __attribute__((ext_vector_type(8)));
typedef float v4f __attribute__((ext_vector_type(4)));

union U8 { int4 i4; v8s v; uint32_t u[4]; };

// gfx950 packed fp32->bf16 convert (RNE)
__device__ __forceinline__ uint32_t pk2(float a, float b) {
  uint32_t r;
  asm("v_cvt_pk_bf16_f32 %0, %1, %2" : "=v"(r) : "v"(a), "v"(b));
  return r;
}

// async global->LDS, 16 B per lane (width=16). LDS dst is wave-uniform base;
// HW scatters lane i to dst + i*16.
__device__ __forceinline__ void glds16(const uint16_t* g, uint16_t* l) {
  __builtin_amdgcn_global_load_lds(
      (const __attribute__((address_space(1))) uint32_t*)g,
      (__attribute__((address_space(3))) uint32_t*)l, 16, 0, 0);
}

// Per-wave self-paced pipeline (no barriers): at each half-phase top,
// ensure prior LDS reads done (guard), issue next half-chunk's 8 glds,
// then wait own loads down to 8 -> current buffer resident.
#define PH_GUARD() asm volatile("s_waitcnt lgkmcnt(0)" ::: "memory")
#define PH_WAIT8() asm volatile("s_waitcnt vmcnt(8)" ::: "memory")
#define PH_WAIT0() asm volatile("s_waitcnt vmcnt(0)" ::: "memory")

// ---- prep: weights -> bf16 frag-order image (W3p negated) ---- (UNCHANGED)
// Wall (uint16_t elems), all frag-order (frag = 512 elems, lane-major):
//   W1t@0      frag(rt,ks2): (rt*2+ks)*512 + lane*8      [8192]
//   W1p@8192   same                                       [8192]
//   W2t@16384  frag(rt,ks4): (rt*4+ks)*512 + lane*8      [16384]
//   W2p@32768                                             [16384]
//   W3t@49152                                             [16384]
//   W3n@65536  (pre-negated pW3)                          [16384]
__global__ void rnd_prep(const float* __restrict__ tW1, const float* __restrict__ tW2,
                         const float* __restrict__ tW3, const float* __restrict__ pW1,
                         const float* __restrict__ pW2, const float* __restrict__ pW3,
                         uint16_t* __restrict__ Wall, float* __restrict__ sums) {
  int g = blockIdx.x * 256 + threadIdx.x;   // 40*256 = 10240 units x 8 elems
  if (g < 2) sums[g] = 0.0f;
  const float* src;
  uint16_t* dst;
  float sgn = 1.f;
  if (g < 2048) {                            // W1 frags (verified R7 pattern)
    int u = g;
    int m = u >> 10; u &= 1023;
    int rt = u >> 7, ks = (u >> 6) & 1, lane = u & 63;
    int n = lane & 15, qq = lane >> 4;
    src = (m ? pW1 : tW1) + (rt * 16 + n) * 64 + ks * 32 + qq * 8;
    dst = Wall + m * 8192 + u * 8;
  } else if (g < 6144) {                     // W2 frags (same 128x128 pattern)
    int u = g - 2048;
    int m = u >> 11; u &= 2047;
    int rt = u >> 8, ks = (u >> 6) & 3, lane = u & 63;
    int n = lane & 15, qq = lane >> 4;
    src = (m ? pW2 : tW2) + (rt * 16 + n) * 128 + ks * 32 + qq * 8;
    dst = Wall + 16384 + m * 16384 + u * 8;
  } else {                                   // W3 frags (predictor negated)
    int u = g - 6144;
    int m = u >> 11; u &= 2047;
    int rt = u >> 8, ks = (u >> 6) & 3, lane = u & 63;
    int n = lane & 15, qq = lane >> 4;
    src = (m ? pW3 : tW3) + (rt * 16 + n) * 128 + ks * 32 + qq * 8;
    sgn = m ? -1.f : 1.f;
    dst = Wall + 49152 + m * 16384 + u * 8;
  }
  float4 f0 = *(const float4*)src, f1 = *(const float4*)(src + 4);
  U8 u8;
  u8.u[0] = pk2(sgn * f0.x, sgn * f0.y); u8.u[1] = pk2(sgn * f0.z, sgn * f0.w);
  u8.u[2] = pk2(sgn * f1.x, sgn * f1.y); u8.u[3] = pk2(sgn * f1.z, sgn * f1.w);
  *(int4*)dst = u8.i4;
}

// ---- main (R18 = R13 resubmit #5, four audits clean): BARRIER-FREE per-wave
// pipeline. R5 post-mortem: counted-vmcnt was null; MfmaUtil stuck at 31%
// because the 10 per-phase barriers keep all 8 waves/CU in lockstep -> stall
// windows (ds latency, pack4 chains, barrier arrival) are correlated and the
// matrix pipe idles ~50% of cycles. Each wave stages its OWN 8KB half-chunks
// into a private 2x8KB LDS ring (4x glds traffic, L2-resident) and self-paces
// with vmcnt(8). Zero barriers between prologue and epilogue; waves drift
// freely so stalls decorrelate. 20 half-phases, each 8 ds_read_b128 + 32 MFMA.
// Half-chunk order (elem offs): W1t 0,4096 | W2t.lo 16384,20480 |
// W2t.hi 24576,28672 | W1p 8192,12288 | W2p.lo 32768,36864 |
// W2p.hi 40960,45056 | W3t.lo 49152,53248 | W3n.lo 65536,69632 |
// W3t.hi 57344,61440 | W3n.hi 73728,77824.  hc_k -> wave buf (k%2). ----
__global__ __launch_bounds__(256, 2) void rnd_main(
    const float* __restrict__ obs, const uint16_t* __restrict__ Wall,
    const float* __restrict__ b1t, const float* __restrict__ b2t,
    const float* __restrict__ b1p, const float* __restrict__ b2p,
    const float* __restrict__ b3t, const float* __restrict__ b3p,
    float* __restrict__ rewards, float* __restrict__ sums) {
  extern __shared__ __align__(16) uint16_t Wl[];  // 4x16KB wave rings + 2560B bias = 68096B
  const int t    = threadIdx.x;
  const int lane = t & 63;
  const int wv   = t >> 6;
  const int n    = lane & 15;
  const int q    = lane >> 4;
  const int s0   = (blockIdx.x * 4 + wv) * 64;

  const uint16_t* gsrc = Wall + lane * 8;          // + hcOff + j*512
  uint16_t*       lwb  = Wl + wv * 8192;           // wave's 16KB (elems); + par*4096
  auto stageh = [&](int hcOff, int par) {          // stage one 8KB half-chunk
    uint16_t* d = lwb + par * 4096;
    #pragma unroll
    for (int j = 0; j < 8; ++j)
      glds16(gsrc + hcOff + j * 512, d + j * 512);
  };
  const uint16_t* rbw = Wl + wv * 8192 + lane * 8; // read base; + par*4096 + f*512
  float* Bl = (float*)(Wl + 32768);                // bias stash @byte 65536, 640 floats
  // Bl: [0]=b1t [128]=b2t [256]=b1p [384]=b2p [512]=b3t-b3p

  // ---- prologue: first half-chunk + bias stash + obs loads ----
  stageh(0, 0);                                    // hc0 W1t.lo -> buf0
  {
    int i = t;
    #pragma unroll
    for (int it = 0; it < 3; ++it, i += 256)
      if (i < 640) {
        int seg = i >> 7, off = i & 127;
        float v;
        if (seg == 0) v = b1t[off];
        else if (seg == 1) v = b2t[off];
        else if (seg == 2) v = b1p[off];
        else if (seg == 3) v = b2p[off];
        else v = b3t[off] - b3p[off];
        Bl[i] = v;
      }
  }
  float4 of[16];
  #pragma unroll
  for (int ct = 0; ct < 4; ++ct)
    #pragma unroll
    for (int ks = 0; ks < 2; ++ks) {
      const float* p = obs + (size_t)(s0 + ct * 16 + n) * OBSD + ks * 32 + q * 8;
      of[(ct * 2 + ks) * 2 + 0] = *(const float4*)p;
      of[(ct * 2 + ks) * 2 + 1] = *(const float4*)(p + 4);
    }
  v8s obf[4][2];
  #pragma unroll
  for (int ct = 0; ct < 4; ++ct)
    #pragma unroll
    for (int ks = 0; ks < 2; ++ks) {
      float4 f0 = of[(ct * 2 + ks) * 2 + 0];
      float4 f1 = of[(ct * 2 + ks) * 2 + 1];
      U8 u;
      u.u[0] = pk2(f0.x, f0.y); u.u[1] = pk2(f0.z, f0.w);
      u.u[2] = pk2(f1.x, f1.y); u.u[3] = pk2(f1.z, f1.w);
      obf[ct][ks] = u.v;
    }

  // bias init for 4 row-tiles (rtBase..rtBase+3) from LDS stash
  auto bias4 = [&](int bbase, int rtBase, v4f (&a)[4][4]) {
    #pragma unroll
    for (int r = 0; r < 4; ++r) {
      v4f c = *(const v4f*)(Bl + bbase + (rtBase + r) * 16 + q * 4);
      #pragma unroll
      for (int ct = 0; ct < 4; ++ct) a[r][ct] = c;
    }
  };
  // bias init for 2 rows (a-rows rB,rB+1 <- stash rows bR,bR+1)
  auto bias2 = [&](int rB, int bR, v4f (&a)[4][4]) {
    #pragma unroll
    for (int r = 0; r < 2; ++r) {
      v4f c = *(const v4f*)(Bl + 512 + (bR + r) * 16 + q * 4);
      #pragma unroll
      for (int ct = 0; ct < 4; ++ct) a[rB + r][ct] = c;
    }
  };
  // ReLU + pack + permlane into B-frag order; rows r0..3 -> BF[ksBase..ksBase+1]
  auto pack4 = [&](v4f (&a)[4][4], v8s (&BF)[4][4], int ksBase) {
    uint32_t P[4][4][2];
    #pragma unroll
    for (int r = 0; r < 4; ++r)
      #pragma unroll
      for (int ct = 0; ct < 4; ++ct) {
        v4f v = a[r][ct];
        v[0] = fmaxf(v[0], 0.f); v[1] = fmaxf(v[1], 0.f);
        v[2] = fmaxf(v[2], 0.f); v[3] = fmaxf(v[3], 0.f);
        P[r][ct][0] = pk2(v[0], v[1]);
        P[r][ct][1] = pk2(v[2], v[3]);
      }
    #pragma unroll
    for (int kk = 0; kk < 2; ++kk)
      #pragma unroll
      for (int ct = 0; ct < 4; ++ct) {
        uint32_t x0 = P[2 * kk][ct][0],     x1 = P[2 * kk][ct][1];
        uint32_t y0 = P[2 * kk + 1][ct][0], y1 = P[2 * kk + 1][ct][1];
        asm("v_permlane32_swap_b32 %0, %1" : "+v"(x0), "+v"(y0));
        asm("v_permlane16_swap_b32 %0, %1" : "+v"(x0), "+v"(y0));
        asm("v_permlane32_swap_b32 %0, %1" : "+v"(x1), "+v"(y1));
        asm("v_permlane16_swap_b32 %0, %1" : "+v"(x1), "+v"(y1));
        U8 u; u.u[0] = x0; u.u[1] = x1; u.u[2] = y0; u.u[3] = y1;
        BF[ksBase + kk][ct] = u.v;
      }
  };
  // layer-1 half (4 rows, frags f=r*2+ks in buf par) -> pack into BF
  auto l1h = [&](int par, int bbase, int rtB, v8s (&BF)[4][4]) {
    v4f a[4][4];
    bias4(bbase, rtB, a);
    __builtin_amdgcn_s_setprio(1);
    #pragma unroll
    for (int ks = 0; ks < 2; ++ks)
      #pragma unroll
      for (int r = 0; r < 4; ++r) {
        U8 u; u.i4 = *(const int4*)(rbw + par * 4096 + (r * 2 + ks) * 512);
        #pragma unroll
        for (int ct = 0; ct < 4; ++ct)
          a[r][ct] = __builtin_amdgcn_mfma_f32_16x16x32_bf16(u.v, obf[ct][ks], a[r][ct], 0, 0, 0);
      }
    __builtin_amdgcn_s_setprio(0);
    pack4(a, BF, rtB >> 1);
  };
  // 2 row-tiles of a 128-wide layer (frags f=rr*4+ks), acc rows rB,rB+1
  auto mm2r = [&](int par, int rB, v8s (&BFin)[4][4], v4f (&a)[4][4]) {
    __builtin_amdgcn_s_setprio(1);
    #pragma unroll
    for (int rr = 0; rr < 2; ++rr)
      #pragma unroll
      for (int ks = 0; ks < 4; ++ks) {
        U8 u; u.i4 = *(const int4*)(rbw + par * 4096 + (rr * 4 + ks) * 512);
        #pragma unroll
        for (int ct = 0; ct < 4; ++ct)
          a[rB + rr][ct] = __builtin_amdgcn_mfma_f32_16x16x32_bf16(u.v, BFin[ks][ct], a[rB + rr][ct], 0, 0, 0);
      }
    __builtin_amdgcn_s_setprio(0);
  };
  float p[4] = {0.f, 0.f, 0.f, 0.f};
  v4f a2[4][4];
  auto reduce4 = [&]() {
    #pragma unroll
    for (int r = 0; r < 4; ++r)
      #pragma unroll
      for (int ct = 0; ct < 4; ++ct) {
        v4f v = a2[r][ct];
        p[ct] += v[0]*v[0] + v[1]*v[1] + v[2]*v[2] + v[3]*v[3];
      }
  };

  v8s BF1[4][4], BF2t[4][4], BF2p[4][4];

  __syncthreads();                                  // bar0: bias stash visible
                                                    // (drains vmcnt -> 0)

  // ---- 20 self-paced half-phases (no barriers) ----
  PH_GUARD(); stageh(4096, 1);  PH_WAIT8();         // hc1 W1t.hi
  l1h(0, 0, 0, BF1);                                // ph0
  PH_GUARD(); stageh(16384, 0); PH_WAIT8();         // hc2 W2t.lo.lo
  l1h(1, 0, 4, BF1);                                // ph1
  PH_GUARD(); stageh(20480, 1); PH_WAIT8();         // hc3
  bias4(128, 0, a2); mm2r(0, 0, BF1, a2);           // ph2
  PH_GUARD(); stageh(24576, 0); PH_WAIT8();         // hc4 W2t.hi.lo
  mm2r(1, 2, BF1, a2); pack4(a2, BF2t, 0);          // ph3
  PH_GUARD(); stageh(28672, 1); PH_WAIT8();         // hc5
  bias4(128, 4, a2); mm2r(0, 0, BF1, a2);           // ph4
  PH_GUARD(); stageh(8192, 0);  PH_WAIT8();         // hc6 W1p.lo
  mm2r(1, 2, BF1, a2); pack4(a2, BF2t, 2);          // ph5
  PH_GUARD(); stageh(12288, 1); PH_WAIT8();         // hc7 W1p.hi
  l1h(0, 256, 0, BF1);                              // ph6
  PH_GUARD(); stageh(32768, 0); PH_WAIT8();         // hc8 W2p.lo.lo
  l1h(1, 256, 4, BF1);                              // ph7
  PH_GUARD(); stageh(36864, 1); PH_WAIT8();         // hc9
  bias4(384, 0, a2); mm2r(0, 0, BF1, a2);           // ph8
  PH_GUARD(); stageh(40960, 0); PH_WAIT8();         // hc10 W2p.hi.lo
  mm2r(1, 2, BF1, a2); pack4(a2, BF2p, 0);          // ph9
  PH_GUARD(); stageh(45056, 1); PH_WAIT8();         // hc11
  bias4(384, 4, a2); mm2r(0, 0, BF1, a2);           // ph10
  PH_GUARD(); stageh(49152, 0); PH_WAIT8();         // hc12 W3t.lo.lo
  mm2r(1, 2, BF1, a2); pack4(a2, BF2p, 2);          // ph11
  PH_GUARD(); stageh(53248, 1); PH_WAIT8();         // hc13
  bias2(0, 0, a2); mm2r(0, 0, BF2t, a2);            // ph12 (acc_lo rows 0,1)
  PH_GUARD(); stageh(65536, 0); PH_WAIT8();         // hc14 W3n.lo.lo
  bias2(2, 2, a2); mm2r(1, 2, BF2t, a2);            // ph13 (rows 2,3)
  PH_GUARD(); stageh(69632, 1); PH_WAIT8();         // hc15
  mm2r(0, 0, BF2p, a2);                             // ph14
  PH_GUARD(); stageh(57344, 0); PH_WAIT8();         // hc16 W3t.hi.lo
  mm2r(1, 2, BF2p, a2); reduce4();                  // ph15 (acc_lo done)
  PH_GUARD(); stageh(61440, 1); PH_WAIT8();         // hc17
  bias2(0, 4, a2); mm2r(0, 0, BF2t, a2);            // ph16 (acc_hi rows 4,5)
  PH_GUARD(); stageh(73728, 0); PH_WAIT8();         // hc18 W3n.hi.lo
  bias2(2, 6, a2); mm2r(1, 2, BF2t, a2);            // ph17 (rows 6,7)
  PH_GUARD(); stageh(77824, 1); PH_WAIT8();         // hc19
  mm2r(0, 0, BF2p, a2);                             // ph18
  PH_WAIT0();                                       // hc19 resident
  mm2r(1, 2, BF2p, a2); reduce4();                  // ph19 (acc_hi done)

  // ---- epilogue: reward = mean over 128 out-dims of diff^2 ----
  float r[4];
  #pragma unroll
  for (int ct = 0; ct < 4; ++ct) {
    p[ct] += __shfl_xor(p[ct], 32);
    p[ct] += __shfl_xor(p[ct], 16);
    r[ct] = p[ct] * (1.0f / 128.0f);
  }
  if (q == 0) {
    #pragma unroll
    for (int ct = 0; ct < 4; ++ct) rewards[s0 + ct * 16 + n] = r[ct];
  }
  float s  = r[0] + r[1] + r[2] + r[3];
  float ss = r[0]*r[0] + r[1]*r[1] + r[2]*r[2] + r[3]*r[3];
  s  += __shfl_xor(s, 8);  s  += __shfl_xor(s, 4);  s  += __shfl_xor(s, 2);  s  += __shfl_xor(s, 1);
  ss += __shfl_xor(ss, 8); ss += __shfl_xor(ss, 4); ss += __shfl_xor(ss, 2); ss += __shfl_xor(ss, 1);
  __syncthreads();                  // all wave work done; reuse Wl as scratch
  float* red = (float*)Wl;
  if (lane == 0) { red[wv] = s; red[8 + wv] = ss; }
  __syncthreads();
  if (t == 0) {
    atomicAdd(&sums[0], red[0] + red[1] + red[2] + red[3]);
    atomicAdd(&sums[1], red[8] + red[9] + red[10] + red[11]);
  }
}

// ---- normalize: Chan-merge with running stats ---- (UNCHANGED)
__global__ void rnd_norm(const float* __restrict__ rewards, const float* __restrict__ sums,
                         const float* __restrict__ rm, const float* __restrict__ rm2,
                         const float* __restrict__ rc, float* __restrict__ out) {
  float S = sums[0], SS = sums[1];
  float nb = (float)BATCH;
  float bm = S / nb;
  float bm2 = SS - nb * bm * bm;
  float cnt = rc[0];
  float newc = cnt + nb;
  float delta = bm - rm[0];
  float newmean = rm[0] + delta * nb / newc;
  float newm2 = rm2[0] + bm2 + delta * delta * cnt * nb / newc;
  float sd = (newc > 1.f) ? sqrtf(newm2 / (newc - 1.f)) : 1.f;
  float inv = 1.f / (sd + 1e-8f);
  int i = (blockIdx.x * 256 + threadIdx.x) * 4;
  float4 r = *(const float4*)(rewards + i);
  float4 o;
  o.x = (r.x - newmean) * inv; o.y = (r.y - newmean) * inv;
  o.z = (r.z - newmean) * inv; o.w = (r.w - newmean) * inv;
  *(float4*)(out + i) = o;
}

extern "C" void kernel_launch(void* const* d_in, const int* in_sizes, int n_in,
                              void* d_out, int out_size, void* d_ws, size_t ws_size,
                              hipStream_t stream) {
  const float* obs = (const float*)d_in[0];
  const float* rm  = (const float*)d_in[1];
  const float* rm2 = (const float*)d_in[2];
  const float* rc  = (const float*)d_in[3];
  const float* tW1 = (const float*)d_in[4];
  const float* tb1 = (const float*)d_in[5];
  const float* tW2 = (const float*)d_in[6];
  const float* tb2 = (const float*)d_in[7];
  const float* tW3 = (const float*)d_in[8];
  const float* tb3 = (const float*)d_in[9];
  const float* pW1 = (const float*)d_in[10];
  const float* pb1 = (const float*)d_in[11];
  const float* pW2 = (const float*)d_in[12];
  const float* pb2 = (const float*)d_in[13];
  const float* pW3 = (const float*)d_in[14];
  const float* pb3 = (const float*)d_in[15];

  float*    sums    = (float*)d_ws;
  float*    rewards = (float*)((char*)d_ws + 256);
  uint16_t* Wall    = (uint16_t*)((char*)d_ws + 256 + (size_t)BATCH * 4);

  (void)hipFuncSetAttribute((const void*)rnd_main,
                            hipFuncAttributeMaxDynamicSharedMemorySize, 68096);

  rnd_prep<<<40, 256, 0, stream>>>(tW1, tW2, tW3, pW1, pW2, pW3, Wall, sums);
  rnd_main<<<BATCH / 256, 256, 68096, stream>>>(obs, Wall, tb1, tb2, pb1, pb2,
                                                tb3, pb3, rewards, sums);
  rnd_norm<<<BATCH / 1024, 256, 0, stream>>>(rewards, sums, rm, rm2, rc, (float*)d_out);
}